// Round 1
// baseline (305.577 us; speedup 1.0000x reference)
//
#include <hip/hip_runtime.h>
#include <hip/hip_bf16.h>

#define HEADS 4
#define DIMH  32
#define HID   128
#define DIM   128
#define NSP   4096
#define QK_SCALE 10.0f

typedef __attribute__((ext_vector_type(4))) float f32x4;
typedef __attribute__((ext_vector_type(8))) short s16x8;

// ---------------- GEMM: Q = W_q @ x  (fp32) ----------------
__global__ __launch_bounds__(256) void k_gemm_q(const float* __restrict__ x,
                                                const float* __restrict__ w,
                                                float* __restrict__ Qf) {
  int blk  = blockIdx.x;            // 2 b * 64 tiles
  int b    = blk >> 6, tile = blk & 63;
  int col  = tile * 64 + (threadIdx.x & 63);
  int wave = threadIdx.x >> 6;
  const float* xb = x + b * DIM * NSP;
  float xc[DIM];
#pragma unroll
  for (int c = 0; c < DIM; ++c) xc[c] = xb[c * NSP + col];
  float* qb = Qf + b * HID * NSP;
  for (int oo = 0; oo < 32; ++oo) {
    int o = wave * 32 + oo;
    const float* wr = w + o * DIM;   // rows 0..127 of w_qkv
    float acc = 0.f;
#pragma unroll
    for (int c = 0; c < DIM; ++c) acc += wr[c] * xc[c];
    qb[o * NSP + col] = acc;
  }
}

// ---------------- GEMM: K (fp32) and V (bf16, natural layout) from y ----------------
__global__ __launch_bounds__(256) void k_gemm_kv(const float* __restrict__ y,
                                                 const float* __restrict__ w,
                                                 float* __restrict__ Kf,
                                                 __hip_bfloat16* __restrict__ Vb) {
  int blk  = blockIdx.x;
  int b    = blk >> 6, tile = blk & 63;
  int col  = tile * 64 + (threadIdx.x & 63);
  int wave = threadIdx.x >> 6;
  const float* yb = y + b * DIM * NSP;
  float yc[DIM];
#pragma unroll
  for (int c = 0; c < DIM; ++c) yc[c] = yb[c * NSP + col];
  float* kb = Kf + b * HID * NSP;
  __hip_bfloat16* vb = Vb + b * HID * NSP;
  for (int oo = 0; oo < 32; ++oo) {
    int o = wave * 32 + oo;
    const float* wr = w + (HID + o) * DIM;   // K rows 128..255
    float acc = 0.f;
#pragma unroll
    for (int c = 0; c < DIM; ++c) acc += wr[c] * yc[c];
    kb[o * NSP + col] = acc;
  }
  for (int oo = 0; oo < 32; ++oo) {
    int o = wave * 32 + oo;
    const float* wr = w + (2 * HID + o) * DIM;  // V rows 256..383
    float acc = 0.f;
#pragma unroll
    for (int c = 0; c < DIM; ++c) acc += wr[c] * yc[c];
    vb[o * NSP + col] = __float2bfloat16(acc);
  }
}

// ---------------- row norms (over spatial axis) for Q and K ----------------
__global__ __launch_bounds__(256) void k_norms(const float* __restrict__ Qf,
                                               const float* __restrict__ Kf,
                                               float* __restrict__ rn) {
  int row = blockIdx.x;  // 0..255 Q rows, 256..511 K rows
  const float* src = (row < 256 ? Qf + row * NSP : Kf + (row - 256) * NSP);
  float ss = 0.f;
  for (int i = threadIdx.x; i < NSP; i += 256) { float v = src[i]; ss += v * v; }
  for (int m = 32; m; m >>= 1) ss += __shfl_xor(ss, m);
  __shared__ float red[4];
  if ((threadIdx.x & 63) == 0) red[threadIdx.x >> 6] = ss;
  __syncthreads();
  if (threadIdx.x == 0) {
    float t = red[0] + red[1] + red[2] + red[3];
    rn[row] = 1.f / fmaxf(sqrtf(t), 1e-12f);
  }
}

// ---------------- normalize + transpose to [b,h,n,32] bf16 ----------------
__global__ __launch_bounds__(256) void k_ntr(const float* __restrict__ Qf,
                                             const float* __restrict__ Kf,
                                             const float* __restrict__ rn,
                                             __hip_bfloat16* __restrict__ Qt,
                                             __hip_bfloat16* __restrict__ Kt) {
  int id   = blockIdx.x;        // 2 tensors * 2 b * 4 h * 32 itiles
  int tens = id >> 8;
  int rem  = id & 255;
  int b = rem >> 7, h = (rem >> 5) & 3, it = rem & 31;
  const float* src = (tens ? Kf : Qf) + (b * HID + h * DIMH) * NSP + it * 128;
  const float* rns = rn + tens * 256 + b * HID + h * DIMH;
  __hip_bfloat16* dst = (tens ? Kt : Qt) + ((size_t)(b * HEADS + h) * NSP + it * 128) * DIMH;

  __shared__ float tile[DIMH][132];
  int d  = threadIdx.x >> 3;
  int cb = (threadIdx.x & 7) * 16;
  float s = rns[d];
#pragma unroll
  for (int k = 0; k < 16; ++k) tile[d][cb + k] = src[d * NSP + cb + k] * s;
  __syncthreads();
  int i = threadIdx.x >> 1, dh = (threadIdx.x & 1) * 16;
  unsigned outw[8];
#pragma unroll
  for (int k = 0; k < 8; ++k) {
    __hip_bfloat16 a = __float2bfloat16(tile[dh + 2 * k][i]);
    __hip_bfloat16 c = __float2bfloat16(tile[dh + 2 * k + 1][i]);
    unsigned lo = *(unsigned short*)&a, hi = *(unsigned short*)&c;
    outw[k] = lo | (hi << 16);
  }
  *(uint4*)(dst + i * DIMH + dh)     = *(uint4*)outw;
  *(uint4*)(dst + i * DIMH + dh + 8) = *(uint4*)(outw + 4);
}

// ---------------- flash attention ----------------
__global__ __launch_bounds__(256) void k_attn(const __hip_bfloat16* __restrict__ Qt,
                                              const __hip_bfloat16* __restrict__ Kt,
                                              const __hip_bfloat16* __restrict__ Vb,
                                              float* __restrict__ Ot) {
  int bh = blockIdx.x >> 6;          // 8
  int it = blockIdx.x & 63;          // 64 q-tiles of 64 rows
  int lane = threadIdx.x & 63, wave = threadIdx.x >> 6;
  int l15 = lane & 15, l4 = lane >> 4;

  __shared__ alignas(16) __hip_bfloat16 Ks[64][40];      // padded: 80B rows
  __shared__ alignas(16) __hip_bfloat16 Vs[32][72];      // padded: 144B rows
  __shared__ alignas(16) __hip_bfloat16 Ps[4][16][72];   // per-wave P tiles

  const __hip_bfloat16* qbase = Qt + ((size_t)bh * NSP + it * 64 + wave * 16) * DIMH;
  s16x8 qa = *(const s16x8*)(qbase + l15 * DIMH + l4 * 8);

  const __hip_bfloat16* kb_g = Kt + (size_t)bh * NSP * DIMH;
  const __hip_bfloat16* vb_g = Vb + (size_t)bh * DIMH * NSP;

  f32x4 oacc[2] = {{0.f, 0.f, 0.f, 0.f}, {0.f, 0.f, 0.f, 0.f}};
  float lpart[4] = {0.f, 0.f, 0.f, 0.f};
  f32x4 zero = {0.f, 0.f, 0.f, 0.f};

  int tid = threadIdx.x;
  int krow = tid >> 2, kslot = tid & 3;   // K tile: 64 rows x 4 x 16B
  int vrow = tid >> 3, vslot = tid & 7;   // V tile: 32 rows x 8 x 16B

  for (int jt = 0; jt < 64; ++jt) {
    int j0 = jt * 64;
    __syncthreads();
    *(s16x8*)&Ks[krow][kslot * 8] = *(const s16x8*)(kb_g + (size_t)(j0 + krow) * DIMH + kslot * 8);
    *(s16x8*)&Vs[vrow][vslot * 8] = *(const s16x8*)(vb_g + (size_t)vrow * NSP + j0 + vslot * 8);
    __syncthreads();

    // QK^T: 4 subtiles of 16 j each, K=32 in one MFMA
#pragma unroll
    for (int c4 = 0; c4 < 4; ++c4) {
      s16x8 kb = *(const s16x8*)&Ks[c4 * 16 + l15][l4 * 8];
      f32x4 s = __builtin_amdgcn_mfma_f32_16x16x32_bf16(qa, kb, zero, 0, 0, 0);
#pragma unroll
      for (int r = 0; r < 4; ++r) {
        float e = __expf(s[r] * QK_SCALE);
        __hip_bfloat16 pb = __float2bfloat16(e);
        Ps[wave][l4 * 4 + r][c4 * 16 + l15] = pb;
        lpart[r] += __bfloat162float(pb);
      }
    }
    __syncthreads();   // P visible within wave; Vs ready

    // PV: out[i][d] += P[i][j] * V[d][j]
#pragma unroll
    for (int jc = 0; jc < 2; ++jc) {
      s16x8 pa = *(const s16x8*)&Ps[wave][l15][jc * 32 + l4 * 8];
#pragma unroll
      for (int dh = 0; dh < 2; ++dh) {
        s16x8 vf = *(const s16x8*)&Vs[dh * 16 + l15][jc * 32 + l4 * 8];
        oacc[dh] = __builtin_amdgcn_mfma_f32_16x16x32_bf16(pa, vf, oacc[dh], 0, 0, 0);
      }
    }
  }

  // reduce row sums across the 16 lanes sharing each row
#pragma unroll
  for (int r = 0; r < 4; ++r) {
    float l = lpart[r];
    l += __shfl_xor(l, 1); l += __shfl_xor(l, 2);
    l += __shfl_xor(l, 4); l += __shfl_xor(l, 8);
    lpart[r] = 1.f / l;
  }
  float* obase = Ot + ((size_t)bh * NSP + it * 64 + wave * 16) * DIMH;
#pragma unroll
  for (int dh = 0; dh < 2; ++dh)
#pragma unroll
    for (int r = 0; r < 4; ++r)
      obase[(size_t)(l4 * 4 + r) * DIMH + dh * 16 + l15] = oacc[dh][r] * lpart[r];
}

// ---------------- output projection ----------------
__global__ __launch_bounds__(256) void k_proj(const float* __restrict__ Ot,
                                              const float* __restrict__ w,
                                              const float* __restrict__ bias,
                                              float* __restrict__ out) {
  int blk  = blockIdx.x;
  int b    = blk >> 6, tile = blk & 63;
  int col  = tile * 64 + (threadIdx.x & 63);
  int wave = threadIdx.x >> 6;
  float hid[HID];
  const float* ob = Ot + (size_t)b * HEADS * NSP * DIMH;
#pragma unroll
  for (int h = 0; h < HEADS; ++h) {
    const float4* src = (const float4*)(ob + ((size_t)h * NSP + col) * DIMH);
#pragma unroll
    for (int k = 0; k < 8; ++k) {
      float4 v = src[k];
      hid[h * 32 + 4 * k + 0] = v.x; hid[h * 32 + 4 * k + 1] = v.y;
      hid[h * 32 + 4 * k + 2] = v.z; hid[h * 32 + 4 * k + 3] = v.w;
    }
  }
  float* outb = out + (size_t)b * DIM * NSP;
  for (int oo = 0; oo < 32; ++oo) {
    int o = wave * 32 + oo;
    const float* wr = w + o * HID;
    float acc = bias[o];
#pragma unroll
    for (int c = 0; c < HID; ++c) acc += wr[c] * hid[c];
    outb[(size_t)o * NSP + col] = acc;
  }
}

extern "C" void kernel_launch(void* const* d_in, const int* in_sizes, int n_in,
                              void* d_out, int out_size, void* d_ws, size_t ws_size,
                              hipStream_t stream) {
  const float* x     = (const float*)d_in[0];
  const float* y     = (const float*)d_in[1];
  const float* w_qkv = (const float*)d_in[2];
  const float* w_out = (const float*)d_in[3];
  const float* b_out = (const float*)d_in[4];
  float* out = (float*)d_out;

  char* ws = (char*)d_ws;
  float* Qf           = (float*)(ws);                       // 4 MB (reused as Ot later)
  float* Kf           = (float*)(ws + (4  << 20));          // 4 MB
  __hip_bfloat16* Vb  = (__hip_bfloat16*)(ws + (8  << 20)); // 2 MB
  __hip_bfloat16* Qt  = (__hip_bfloat16*)(ws + (10 << 20)); // 2 MB
  __hip_bfloat16* Kt  = (__hip_bfloat16*)(ws + (12 << 20)); // 2 MB
  float* Ot           = (float*)(ws + (14 << 20));          // 4 MB
  float* rn           = (float*)(ws + (18 << 20));          // 2 KB

  k_gemm_q <<<128, 256, 0, stream>>>(x, w_qkv, Qf);
  k_gemm_kv<<<128, 256, 0, stream>>>(y, w_qkv, Kf, Vb);
  k_norms  <<<512, 256, 0, stream>>>(Qf, Kf, rn);
  k_ntr    <<<512, 256, 0, stream>>>(Qf, Kf, rn, Qt, Kt);
  k_attn   <<<512, 256, 0, stream>>>(Qt, Kt, Vb, Ot);
  k_proj   <<<128, 256, 0, stream>>>(Ot, w_out, b_out, out);
}

// Round 2
// 140.185 us; speedup vs baseline: 2.1798x; 2.1798x over previous
//
#include <hip/hip_runtime.h>
#include <hip/hip_bf16.h>

#define HEADS 4
#define DIMH  32
#define HID   128
#define DIM   128
#define NSP   4096
#define QK_SCALE 10.0f

typedef __attribute__((ext_vector_type(4))) float f32x4;
typedef __attribute__((ext_vector_type(8))) short s16x8;

// ---------------- GEMM: Q = W_q @ x (fp32), uniform-weight structure ----------------
// grid = 16 o-chunks (8 outputs) x 32 col-tiles (256 cols). Weight rows depend only
// on blockIdx -> s_load; per-thread column cached in VGPRs.
__global__ __launch_bounds__(256) void k_gemm_q(const float* __restrict__ x,
                                                const float* __restrict__ w,
                                                float* __restrict__ Qf) {
  int ct = blockIdx.x & 31;
  int oc = blockIdx.x >> 5;          // 0..15
  int g  = ct * 256 + threadIdx.x;   // global col in [0, 8192)
  int b  = g >> 12, n = g & 4095;
  const float* xp = x + ((size_t)b * DIM) * NSP + n;
  float xc[DIM];
#pragma unroll
  for (int c = 0; c < DIM; ++c) xc[c] = xp[(size_t)c * NSP];
  float acc[8];
#pragma unroll
  for (int i = 0; i < 8; ++i) acc[i] = 0.f;
#pragma unroll
  for (int c = 0; c < DIM; ++c) {
    float xv = xc[c];
#pragma unroll
    for (int i = 0; i < 8; ++i) acc[i] += w[(oc * 8 + i) * DIM + c] * xv;
  }
  float* qb = Qf + (size_t)b * HID * NSP + n;
#pragma unroll
  for (int i = 0; i < 8; ++i) qb[(size_t)(oc * 8 + i) * NSP] = acc[i];
}

// ---------------- GEMM: K (fp32) + V (bf16) from y ----------------
// grid = 16 o-chunks (16 outputs) x 32 col-tiles
__global__ __launch_bounds__(256) void k_gemm_kv(const float* __restrict__ y,
                                                 const float* __restrict__ w,
                                                 float* __restrict__ Kf,
                                                 __hip_bfloat16* __restrict__ Vb) {
  int ct = blockIdx.x & 31;
  int oc = blockIdx.x >> 5;          // 0..15
  int g  = ct * 256 + threadIdx.x;
  int b  = g >> 12, n = g & 4095;
  const float* yp = y + ((size_t)b * DIM) * NSP + n;
  float yc[DIM];
#pragma unroll
  for (int c = 0; c < DIM; ++c) yc[c] = yp[(size_t)c * NSP];
  float acc[16];
#pragma unroll
  for (int i = 0; i < 16; ++i) acc[i] = 0.f;
#pragma unroll
  for (int c = 0; c < DIM; ++c) {
    float yv = yc[c];
#pragma unroll
    for (int i = 0; i < 16; ++i) acc[i] += w[(HID + oc * 16 + i) * DIM + c] * yv;
  }
#pragma unroll
  for (int i = 0; i < 16; ++i) {
    int o = oc * 16 + i;
    if (o < HID) {
      Kf[((size_t)b * HID + o) * NSP + n] = acc[i];
    } else {
      Vb[((size_t)b * HID + (o - HID)) * NSP + n] = __float2bfloat16(acc[i]);
    }
  }
}

// ---------------- row norms (over spatial axis) for Q and K ----------------
__global__ __launch_bounds__(256) void k_norms(const float* __restrict__ Qf,
                                               const float* __restrict__ Kf,
                                               float* __restrict__ rn) {
  int row = blockIdx.x;  // 0..255 Q rows, 256..511 K rows
  const float* src = (row < 256 ? Qf + (size_t)row * NSP : Kf + (size_t)(row - 256) * NSP);
  float ss = 0.f;
  for (int i = threadIdx.x; i < NSP; i += 256) { float v = src[i]; ss += v * v; }
  for (int m = 32; m; m >>= 1) ss += __shfl_xor(ss, m);
  __shared__ float red[4];
  if ((threadIdx.x & 63) == 0) red[threadIdx.x >> 6] = ss;
  __syncthreads();
  if (threadIdx.x == 0) {
    float t = red[0] + red[1] + red[2] + red[3];
    rn[row] = 1.f / fmaxf(sqrtf(t), 1e-12f);
  }
}

// ---------------- normalize + transpose to [b,h,n,32] bf16 ----------------
__global__ __launch_bounds__(256) void k_ntr(const float* __restrict__ Qf,
                                             const float* __restrict__ Kf,
                                             const float* __restrict__ rn,
                                             __hip_bfloat16* __restrict__ Qt,
                                             __hip_bfloat16* __restrict__ Kt) {
  int id   = blockIdx.x;        // 2 tensors * 2 b * 4 h * 32 itiles
  int tens = id >> 8;
  int rem  = id & 255;
  int b = rem >> 7, h = (rem >> 5) & 3, it = rem & 31;
  const float* src = (tens ? Kf : Qf) + ((size_t)(b * HID + h * DIMH)) * NSP + it * 128;
  const float* rns = rn + tens * 256 + b * HID + h * DIMH;
  __hip_bfloat16* dst = (tens ? Kt : Qt) + ((size_t)(b * HEADS + h) * NSP + it * 128) * DIMH;

  __shared__ float tile[DIMH][132];
  int d  = threadIdx.x >> 3;
  int cb = (threadIdx.x & 7) * 16;
  float s = rns[d];
#pragma unroll
  for (int k = 0; k < 16; ++k) tile[d][cb + k] = src[(size_t)d * NSP + cb + k] * s;
  __syncthreads();
  int i = threadIdx.x >> 1, dh = (threadIdx.x & 1) * 16;
  unsigned outw[8];
#pragma unroll
  for (int k = 0; k < 8; ++k) {
    __hip_bfloat16 a = __float2bfloat16(tile[dh + 2 * k][i]);
    __hip_bfloat16 c = __float2bfloat16(tile[dh + 2 * k + 1][i]);
    unsigned lo = *(unsigned short*)&a, hi = *(unsigned short*)&c;
    outw[k] = lo | (hi << 16);
  }
  *(uint4*)(dst + i * DIMH + dh)     = *(uint4*)outw;
  *(uint4*)(dst + i * DIMH + dh + 8) = *(uint4*)(outw + 4);
}

// ---------------- flash attention ----------------
__global__ __launch_bounds__(256) void k_attn(const __hip_bfloat16* __restrict__ Qt,
                                              const __hip_bfloat16* __restrict__ Kt,
                                              const __hip_bfloat16* __restrict__ Vb,
                                              float* __restrict__ Ot) {
  int bh = blockIdx.x >> 6;          // 8
  int it = blockIdx.x & 63;          // 64 q-tiles of 64 rows
  int lane = threadIdx.x & 63, wave = threadIdx.x >> 6;
  int l15 = lane & 15, l4 = lane >> 4;

  __shared__ alignas(16) __hip_bfloat16 Ks[64][40];      // padded: 80B rows
  __shared__ alignas(16) __hip_bfloat16 Vs[32][72];      // padded: 144B rows
  __shared__ alignas(16) __hip_bfloat16 Ps[4][16][72];   // per-wave P tiles

  const __hip_bfloat16* qbase = Qt + ((size_t)bh * NSP + it * 64 + wave * 16) * DIMH;
  s16x8 qa = *(const s16x8*)(qbase + l15 * DIMH + l4 * 8);

  const __hip_bfloat16* kb_g = Kt + (size_t)bh * NSP * DIMH;
  const __hip_bfloat16* vb_g = Vb + (size_t)bh * DIMH * NSP;

  f32x4 oacc[2] = {{0.f, 0.f, 0.f, 0.f}, {0.f, 0.f, 0.f, 0.f}};
  float lpart[4] = {0.f, 0.f, 0.f, 0.f};
  f32x4 zero = {0.f, 0.f, 0.f, 0.f};

  int tid = threadIdx.x;
  int krow = tid >> 2, kslot = tid & 3;   // K tile: 64 rows x 4 x 16B
  int vrow = tid >> 3, vslot = tid & 7;   // V tile: 32 rows x 8 x 16B

  for (int jt = 0; jt < 64; ++jt) {
    int j0 = jt * 64;
    __syncthreads();
    *(s16x8*)&Ks[krow][kslot * 8] = *(const s16x8*)(kb_g + (size_t)(j0 + krow) * DIMH + kslot * 8);
    *(s16x8*)&Vs[vrow][vslot * 8] = *(const s16x8*)(vb_g + (size_t)vrow * NSP + j0 + vslot * 8);
    __syncthreads();

    // QK^T: 4 subtiles of 16 j each, K=32 in one MFMA
#pragma unroll
    for (int c4 = 0; c4 < 4; ++c4) {
      s16x8 kb = *(const s16x8*)&Ks[c4 * 16 + l15][l4 * 8];
      f32x4 s = __builtin_amdgcn_mfma_f32_16x16x32_bf16(qa, kb, zero, 0, 0, 0);
#pragma unroll
      for (int r = 0; r < 4; ++r) {
        float e = __expf(s[r] * QK_SCALE);
        __hip_bfloat16 pb = __float2bfloat16(e);
        Ps[wave][l4 * 4 + r][c4 * 16 + l15] = pb;
        lpart[r] += __bfloat162float(pb);
      }
    }
    __syncthreads();   // P visible within wave; Vs ready

    // PV: out[i][d] += P[i][j] * V[d][j]
#pragma unroll
    for (int jc = 0; jc < 2; ++jc) {
      s16x8 pa = *(const s16x8*)&Ps[wave][l15][jc * 32 + l4 * 8];
#pragma unroll
      for (int dh = 0; dh < 2; ++dh) {
        s16x8 vf = *(const s16x8*)&Vs[dh * 16 + l15][jc * 32 + l4 * 8];
        oacc[dh] = __builtin_amdgcn_mfma_f32_16x16x32_bf16(pa, vf, oacc[dh], 0, 0, 0);
      }
    }
  }

  // reduce row sums across the 16 lanes sharing each row
#pragma unroll
  for (int r = 0; r < 4; ++r) {
    float l = lpart[r];
    l += __shfl_xor(l, 1); l += __shfl_xor(l, 2);
    l += __shfl_xor(l, 4); l += __shfl_xor(l, 8);
    lpart[r] = 1.f / l;
  }
  float* obase = Ot + ((size_t)bh * NSP + it * 64 + wave * 16) * DIMH;
#pragma unroll
  for (int dh = 0; dh < 2; ++dh)
#pragma unroll
    for (int r = 0; r < 4; ++r)
      obase[(size_t)(l4 * 4 + r) * DIMH + dh * 16 + l15] = oacc[dh][r] * lpart[r];
}

// ---------------- output projection ----------------
// grid = 16 o-chunks (8 outputs) x 32 col-tiles; weight rows uniform from blockIdx
__global__ __launch_bounds__(256) void k_proj(const float* __restrict__ Ot,
                                              const float* __restrict__ w,
                                              const float* __restrict__ bias,
                                              float* __restrict__ out) {
  int ct = blockIdx.x & 31;
  int oc = blockIdx.x >> 5;          // 0..15
  int g  = ct * 256 + threadIdx.x;
  int b  = g >> 12, n = g & 4095;
  float hid[HID];
  const float* ob = Ot + (size_t)b * HEADS * NSP * DIMH;
#pragma unroll
  for (int h = 0; h < HEADS; ++h) {
    const f32x4* src = (const f32x4*)(ob + ((size_t)h * NSP + n) * DIMH);
#pragma unroll
    for (int k = 0; k < 8; ++k) {
      f32x4 v = src[k];
      hid[h * 32 + 4 * k + 0] = v[0]; hid[h * 32 + 4 * k + 1] = v[1];
      hid[h * 32 + 4 * k + 2] = v[2]; hid[h * 32 + 4 * k + 3] = v[3];
    }
  }
  float acc[8];
#pragma unroll
  for (int i = 0; i < 8; ++i) acc[i] = bias[oc * 8 + i];
#pragma unroll
  for (int c = 0; c < HID; ++c) {
    float hv = hid[c];
#pragma unroll
    for (int i = 0; i < 8; ++i) acc[i] += w[(oc * 8 + i) * HID + c] * hv;
  }
  float* outb = out + (size_t)b * DIM * NSP + n;
#pragma unroll
  for (int i = 0; i < 8; ++i) outb[(size_t)(oc * 8 + i) * NSP] = acc[i];
}

extern "C" void kernel_launch(void* const* d_in, const int* in_sizes, int n_in,
                              void* d_out, int out_size, void* d_ws, size_t ws_size,
                              hipStream_t stream) {
  const float* x     = (const float*)d_in[0];
  const float* y     = (const float*)d_in[1];
  const float* w_qkv = (const float*)d_in[2];
  const float* w_out = (const float*)d_in[3];
  const float* b_out = (const float*)d_in[4];
  float* out = (float*)d_out;

  char* ws = (char*)d_ws;
  float* Qf           = (float*)(ws);                       // 4 MB
  float* Kf           = (float*)(ws + (4  << 20));          // 4 MB
  __hip_bfloat16* Vb  = (__hip_bfloat16*)(ws + (8  << 20)); // 2 MB
  __hip_bfloat16* Qt  = (__hip_bfloat16*)(ws + (10 << 20)); // 2 MB
  __hip_bfloat16* Kt  = (__hip_bfloat16*)(ws + (12 << 20)); // 2 MB
  float* Ot           = (float*)(ws + (14 << 20));          // 4 MB
  float* rn           = (float*)(ws + (18 << 20));          // 2 KB

  k_gemm_q <<<512, 256, 0, stream>>>(x, w_qkv, Qf);
  k_gemm_kv<<<512, 256, 0, stream>>>(y, w_qkv, Kf, Vb);
  k_norms  <<<512, 256, 0, stream>>>(Qf, Kf, rn);
  k_ntr    <<<512, 256, 0, stream>>>(Qf, Kf, rn, Qt, Kt);
  k_attn   <<<512, 256, 0, stream>>>(Qt, Kt, Vb, Ot);
  k_proj   <<<512, 256, 0, stream>>>(Ot, w_out, b_out, out);
}

// Round 4
// 121.739 us; speedup vs baseline: 2.5101x; 1.1515x over previous
//
#include <hip/hip_runtime.h>
#include <hip/hip_bf16.h>

#define HEADS 4
#define DIMH  32
#define HID   128
#define DIM   128
#define NSP   4096
// 10 * log2(e) folded into Qt at k_ntr time; attention uses exp2 directly.
#define QSCALE_LOG2E 14.426950408889634f

typedef __attribute__((ext_vector_type(4)))  float f32x4;
typedef __attribute__((ext_vector_type(16))) float f32x16;
typedef __attribute__((ext_vector_type(8)))  short s16x8;

// ---------------- GEMM: Q = W_q @ x (fp32), uniform-weight structure ----------------
__global__ __launch_bounds__(256) void k_gemm_q(const float* __restrict__ x,
                                                const float* __restrict__ w,
                                                float* __restrict__ Qf) {
  int ct = blockIdx.x & 31;
  int oc = blockIdx.x >> 5;          // 0..15
  int g  = ct * 256 + threadIdx.x;   // global col in [0, 8192)
  int b  = g >> 12, n = g & 4095;
  const float* xp = x + ((size_t)b * DIM) * NSP + n;
  float xc[DIM];
#pragma unroll
  for (int c = 0; c < DIM; ++c) xc[c] = xp[(size_t)c * NSP];
  float acc[8];
#pragma unroll
  for (int i = 0; i < 8; ++i) acc[i] = 0.f;
#pragma unroll
  for (int c = 0; c < DIM; ++c) {
    float xv = xc[c];
#pragma unroll
    for (int i = 0; i < 8; ++i) acc[i] += w[(oc * 8 + i) * DIM + c] * xv;
  }
  float* qb = Qf + (size_t)b * HID * NSP + n;
#pragma unroll
  for (int i = 0; i < 8; ++i) qb[(size_t)(oc * 8 + i) * NSP] = acc[i];
}

// ---------------- GEMM: K (fp32) + V (bf16) from y ----------------
__global__ __launch_bounds__(256) void k_gemm_kv(const float* __restrict__ y,
                                                 const float* __restrict__ w,
                                                 float* __restrict__ Kf,
                                                 __hip_bfloat16* __restrict__ Vb) {
  int ct = blockIdx.x & 31;
  int oc = blockIdx.x >> 5;          // 0..15
  int g  = ct * 256 + threadIdx.x;
  int b  = g >> 12, n = g & 4095;
  const float* yp = y + ((size_t)b * DIM) * NSP + n;
  float yc[DIM];
#pragma unroll
  for (int c = 0; c < DIM; ++c) yc[c] = yp[(size_t)c * NSP];
  float acc[16];
#pragma unroll
  for (int i = 0; i < 16; ++i) acc[i] = 0.f;
#pragma unroll
  for (int c = 0; c < DIM; ++c) {
    float yv = yc[c];
#pragma unroll
    for (int i = 0; i < 16; ++i) acc[i] += w[(HID + oc * 16 + i) * DIM + c] * yv;
  }
#pragma unroll
  for (int i = 0; i < 16; ++i) {
    int o = oc * 16 + i;
    if (o < HID) {
      Kf[((size_t)b * HID + o) * NSP + n] = acc[i];
    } else {
      Vb[((size_t)b * HID + (o - HID)) * NSP + n] = __float2bfloat16(acc[i]);
    }
  }
}

// ---------------- row norms (over spatial axis) for Q and K ----------------
__global__ __launch_bounds__(256) void k_norms(const float* __restrict__ Qf,
                                               const float* __restrict__ Kf,
                                               float* __restrict__ rn) {
  int row = blockIdx.x;  // 0..255 Q rows, 256..511 K rows
  const float* src = (row < 256 ? Qf + (size_t)row * NSP : Kf + (size_t)(row - 256) * NSP);
  float ss = 0.f;
  for (int i = threadIdx.x; i < NSP; i += 256) { float v = src[i]; ss += v * v; }
  for (int m = 32; m; m >>= 1) ss += __shfl_xor(ss, m);
  __shared__ float red[4];
  if ((threadIdx.x & 63) == 0) red[threadIdx.x >> 6] = ss;
  __syncthreads();
  if (threadIdx.x == 0) {
    float t = red[0] + red[1] + red[2] + red[3];
    rn[row] = 1.f / fmaxf(sqrtf(t), 1e-12f);
  }
}

// ---------------- normalize + transpose to [b,h,n,32] bf16 (Q gets exp2 scale) ----------------
__global__ __launch_bounds__(256) void k_ntr(const float* __restrict__ Qf,
                                             const float* __restrict__ Kf,
                                             const float* __restrict__ rn,
                                             __hip_bfloat16* __restrict__ Qt,
                                             __hip_bfloat16* __restrict__ Kt) {
  int id   = blockIdx.x;        // 2 tensors * 2 b * 4 h * 32 itiles
  int tens = id >> 8;
  int rem  = id & 255;
  int b = rem >> 7, h = (rem >> 5) & 3, it = rem & 31;
  const float* src = (tens ? Kf : Qf) + ((size_t)(b * HID + h * DIMH)) * NSP + it * 128;
  const float* rns = rn + tens * 256 + b * HID + h * DIMH;
  __hip_bfloat16* dst = (tens ? Kt : Qt) + ((size_t)(b * HEADS + h) * NSP + it * 128) * DIMH;

  __shared__ float tile[DIMH][132];
  int d  = threadIdx.x >> 3;
  int cb = (threadIdx.x & 7) * 16;
  float s = rns[d] * (tens ? 1.f : QSCALE_LOG2E);
#pragma unroll
  for (int k = 0; k < 16; ++k) tile[d][cb + k] = src[(size_t)d * NSP + cb + k] * s;
  __syncthreads();
  int i = threadIdx.x >> 1, dh = (threadIdx.x & 1) * 16;
  unsigned outw[8];
#pragma unroll
  for (int k = 0; k < 8; ++k) {
    __hip_bfloat16 a = __float2bfloat16(tile[dh + 2 * k][i]);
    __hip_bfloat16 c = __float2bfloat16(tile[dh + 2 * k + 1][i]);
    unsigned lo = *(unsigned short*)&a, hi = *(unsigned short*)&c;
    outw[k] = lo | (hi << 16);
  }
  *(uint4*)(dst + i * DIMH + dh)     = *(uint4*)outw;
  *(uint4*)(dst + i * DIMH + dh + 8) = *(uint4*)(outw + 4);
}

// ---------------- flash attention: 32x32x16 MFMA, in-register softmax ----------------
__device__ __forceinline__ unsigned cvtpk_bf16(float a, float b) {
  unsigned d;
  asm("v_cvt_pk_bf16_f32 %0, %1, %2" : "=v"(d) : "v"(a), "v"(b));
  return d;
}

struct KV { s16x8 k[2][2]; s16x8 v[4]; };

__device__ __forceinline__ KV ldkv(const __hip_bfloat16* kp, const __hip_bfloat16* vp, int j0) {
  KV f;
#pragma unroll
  for (int s = 0; s < 2; ++s)
#pragma unroll
    for (int kh = 0; kh < 2; ++kh)
      f.k[s][kh] = *(const s16x8*)(kp + (size_t)(j0 + s * 32) * DIMH + kh * 16);
#pragma unroll
  for (int cc = 0; cc < 4; ++cc)
    f.v[cc] = *(const s16x8*)(vp + j0 + cc * 16);
  return f;
}

__device__ __forceinline__ void attn_step(const KV& f, const s16x8* qb,
                                          f32x16& O, float& lsum) {
  f32x16 z = {};
  f32x16 s0 = __builtin_amdgcn_mfma_f32_32x32x16_bf16(f.k[0][0], qb[0], z, 0, 0, 0);
  s0        = __builtin_amdgcn_mfma_f32_32x32x16_bf16(f.k[0][1], qb[1], s0, 0, 0, 0);
  f32x16 s1 = __builtin_amdgcn_mfma_f32_32x32x16_bf16(f.k[1][0], qb[0], z, 0, 0, 0);
  s1        = __builtin_amdgcn_mfma_f32_32x32x16_bf16(f.k[1][1], qb[1], s1, 0, 0, 0);
  float p0[16], p1[16];
#pragma unroll
  for (int r = 0; r < 16; ++r) { p0[r] = __builtin_amdgcn_exp2f(s0[r]); lsum += p0[r]; }
#pragma unroll
  for (int r = 0; r < 16; ++r) { p1[r] = __builtin_amdgcn_exp2f(s1[r]); lsum += p1[r]; }
  unsigned wA0[4], wB0[4], wA1[4], wB1[4];
#pragma unroll
  for (int m = 0; m < 4; ++m) {
    wA0[m] = cvtpk_bf16(p0[4 * m], p0[4 * m + 1]);
    wB0[m] = cvtpk_bf16(p0[4 * m + 2], p0[4 * m + 3]);
    wA1[m] = cvtpk_bf16(p1[4 * m], p1[4 * m + 1]);
    wB1[m] = cvtpk_bf16(p1[4 * m + 2], p1[4 * m + 3]);
  }
  // chunk cc: j in [cc*16, cc*16+16); subtile s=cc>>1, c=cc&1.
  // swap(wA[2c], wA[2c+1]) -> (dword0, dword2); wB pair -> (dword1, dword3)
#define PV_CHUNK(WA, WB, c, vfrag)                                             \
  {                                                                            \
    unsigned a0 = WA[2 * (c)], a1 = WA[2 * (c) + 1];                           \
    unsigned b0 = WB[2 * (c)], b1 = WB[2 * (c) + 1];                           \
    asm("v_permlane32_swap_b32 %0, %1" : "+v"(a0), "+v"(a1));                  \
    asm("v_permlane32_swap_b32 %0, %1" : "+v"(b0), "+v"(b1));                  \
    union { unsigned u[4]; s16x8 v; } pa;                                      \
    pa.u[0] = a0; pa.u[1] = b0; pa.u[2] = a1; pa.u[3] = b1;                    \
    O = __builtin_amdgcn_mfma_f32_32x32x16_bf16(pa.v, vfrag, O, 0, 0, 0);      \
  }
  PV_CHUNK(wA0, wB0, 0, f.v[0]);
  PV_CHUNK(wA0, wB0, 1, f.v[1]);
  PV_CHUNK(wA1, wB1, 0, f.v[2]);
  PV_CHUNK(wA1, wB1, 1, f.v[3]);
#undef PV_CHUNK
}

__global__ __launch_bounds__(512) void k_attn(const __hip_bfloat16* __restrict__ Qt,
                                              const __hip_bfloat16* __restrict__ Kt,
                                              const __hip_bfloat16* __restrict__ Vb,
                                              float* __restrict__ Ot) {
  int bid = blockIdx.x;
  int swz = (bid & 7) * 32 + (bid >> 3);   // XCD-contiguous bh
  int bh = swz >> 5, qt = swz & 31;
  int tid = threadIdx.x, lane = tid & 63, wave = tid >> 6;
  int l31 = lane & 31, hi = lane >> 5;
  int qsub = wave & 3, jhalf = wave >> 2;
  int i0 = qt * 128 + qsub * 32;

  const __hip_bfloat16* kp = Kt + ((size_t)bh * NSP + l31) * DIMH + hi * 8;
  const __hip_bfloat16* vp = Vb + ((size_t)bh * DIMH + l31) * NSP + hi * 8;
  const __hip_bfloat16* qp = Qt + ((size_t)bh * NSP + i0 + l31) * DIMH + hi * 8;
  s16x8 qb[2] = { *(const s16x8*)qp, *(const s16x8*)(qp + 16) };

  f32x16 O = {};
  float lsum = 0.f;
  int jbase = jhalf * 2048;

  KV fA = ldkv(kp, vp, jbase);
  for (int t = 0; t < 32; t += 2) {
    KV fB = ldkv(kp, vp, jbase + (t + 1) * 64);
    attn_step(fA, qb, O, lsum);
    fA = ldkv(kp, vp, jbase + ((t + 2) & 31) * 64);  // wraps harmlessly on last iter
    attn_step(fB, qb, O, lsum);
  }

  // merge the two KV-halves (wave pairs) via LDS; no max-tracking needed
  __shared__ float Olds[4][16][64];
  __shared__ float Llds[4][64];
  float lw = lsum + __shfl_xor(lsum, 32);   // wave-total row sum for i = l31
  if (jhalf == 1) {
#pragma unroll
    for (int r = 0; r < 16; ++r) Olds[qsub][r][lane] = O[r];
    Llds[qsub][lane] = lw;
  }
  __syncthreads();
  if (jhalf == 0) {
    float ltot = lw + Llds[qsub][lane];     // total l for row i = l31
    if (hi == 0) Llds[qsub][l31] = ltot;    // reindex by row (in-wave order: read above, then write)
    float* obase = Ot + ((size_t)bh * NSP + i0) * DIMH + l31;
#pragma unroll
    for (int r = 0; r < 16; ++r) {
      int i = (r & 3) + 8 * (r >> 2) + 4 * hi;
      float li = Llds[qsub][i];
      obase[(size_t)i * DIMH] = (O[r] + Olds[qsub][r][lane]) / li;
    }
  }
}

// ---------------- output projection ----------------
__global__ __launch_bounds__(256) void k_proj(const float* __restrict__ Ot,
                                              const float* __restrict__ w,
                                              const float* __restrict__ bias,
                                              float* __restrict__ out) {
  int ct = blockIdx.x & 31;
  int oc = blockIdx.x >> 5;          // 0..15
  int g  = ct * 256 + threadIdx.x;
  int b  = g >> 12, n = g & 4095;
  float hid[HID];
  const float* ob = Ot + (size_t)b * HEADS * NSP * DIMH;
#pragma unroll
  for (int h = 0; h < HEADS; ++h) {
    const f32x4* src = (const f32x4*)(ob + ((size_t)h * NSP + n) * DIMH);
#pragma unroll
    for (int k = 0; k < 8; ++k) {
      f32x4 v = src[k];
      hid[h * 32 + 4 * k + 0] = v[0]; hid[h * 32 + 4 * k + 1] = v[1];
      hid[h * 32 + 4 * k + 2] = v[2]; hid[h * 32 + 4 * k + 3] = v[3];
    }
  }
  float acc[8];
#pragma unroll
  for (int i = 0; i < 8; ++i) acc[i] = bias[oc * 8 + i];
#pragma unroll
  for (int c = 0; c < HID; ++c) {
    float hv = hid[c];
#pragma unroll
    for (int i = 0; i < 8; ++i) acc[i] += w[(oc * 8 + i) * HID + c] * hv;
  }
  float* outb = out + (size_t)b * DIM * NSP + n;
#pragma unroll
  for (int i = 0; i < 8; ++i) outb[(size_t)(oc * 8 + i) * NSP] = acc[i];
}

extern "C" void kernel_launch(void* const* d_in, const int* in_sizes, int n_in,
                              void* d_out, int out_size, void* d_ws, size_t ws_size,
                              hipStream_t stream) {
  const float* x     = (const float*)d_in[0];
  const float* y     = (const float*)d_in[1];
  const float* w_qkv = (const float*)d_in[2];
  const float* w_out = (const float*)d_in[3];
  const float* b_out = (const float*)d_in[4];
  float* out = (float*)d_out;

  char* ws = (char*)d_ws;
  float* Qf           = (float*)(ws);                       // 4 MB
  float* Kf           = (float*)(ws + (4  << 20));          // 4 MB
  __hip_bfloat16* Vb  = (__hip_bfloat16*)(ws + (8  << 20)); // 2 MB
  __hip_bfloat16* Qt  = (__hip_bfloat16*)(ws + (10 << 20)); // 2 MB
  __hip_bfloat16* Kt  = (__hip_bfloat16*)(ws + (12 << 20)); // 2 MB
  float* Ot           = (float*)(ws + (14 << 20));          // 4 MB
  float* rn           = (float*)(ws + (18 << 20));          // 2 KB

  k_gemm_q <<<512, 256, 0, stream>>>(x, w_qkv, Qf);
  k_gemm_kv<<<512, 256, 0, stream>>>(y, w_qkv, Kf, Vb);
  k_norms  <<<512, 256, 0, stream>>>(Qf, Kf, rn);
  k_ntr    <<<512, 256, 0, stream>>>(Qf, Kf, rn, Qt, Kt);
  k_attn   <<<256, 512, 0, stream>>>(Qt, Kt, Vb, Ot);
  k_proj   <<<512, 256, 0, stream>>>(Ot, w_out, b_out, out);
}

// Round 5
// 107.472 us; speedup vs baseline: 2.8433x; 1.1328x over previous
//
#include <hip/hip_runtime.h>
#include <hip/hip_bf16.h>

#define HEADS 4
#define DIMH  32
#define HID   128
#define DIM   128
#define NSP   4096
// 10 * log2(e) folded into Qt at k_ntr time; attention uses exp2 directly.
#define QSCALE_LOG2E 14.426950408889634f

typedef __attribute__((ext_vector_type(4)))  float f32x4;
typedef __attribute__((ext_vector_type(16))) float f32x16;
typedef __attribute__((ext_vector_type(8)))  short s16x8;

// ---------------- GEMM: Q = W_q @ x (fp32) ----------------
// grid = 32 oc (4 outs) x 64 ct (128 cols), block 128. Weight rows blockIdx-uniform -> s_load.
__global__ __launch_bounds__(128, 4) void k_gemm_q(const float* __restrict__ x,
                                                   const float* __restrict__ w,
                                                   float* __restrict__ Qf) {
  int ct = blockIdx.x & 63, oc = blockIdx.x >> 6;
  int g = ct * 128 + threadIdx.x;
  int b = g >> 12, n = g & 4095;
  const float* xp = x + (size_t)b * DIM * NSP + n;
  float acc[4] = {0.f, 0.f, 0.f, 0.f};
#pragma unroll 1
  for (int c0 = 0; c0 < DIM; c0 += 32) {
    float xc[32];
#pragma unroll
    for (int cc = 0; cc < 32; ++cc) xc[cc] = xp[(size_t)(c0 + cc) * NSP];
#pragma unroll
    for (int cc = 0; cc < 32; ++cc)
#pragma unroll
      for (int i = 0; i < 4; ++i)
        acc[i] += w[(oc * 4 + i) * DIM + c0 + cc] * xc[cc];
  }
  float* qb = Qf + (size_t)b * HID * NSP + n;
#pragma unroll
  for (int i = 0; i < 4; ++i) qb[(size_t)(oc * 4 + i) * NSP] = acc[i];
}

// ---------------- GEMM: K (fp32) + V (bf16) from y ----------------
// grid = 32 oc (8 outs) x 64 ct, block 128. oc<16 -> K rows, else V rows.
__global__ __launch_bounds__(128, 4) void k_gemm_kv(const float* __restrict__ y,
                                                    const float* __restrict__ w,
                                                    float* __restrict__ Kf,
                                                    __hip_bfloat16* __restrict__ Vb) {
  int ct = blockIdx.x & 63, oc = blockIdx.x >> 6;   // 0..31
  int g = ct * 128 + threadIdx.x;
  int b = g >> 12, n = g & 4095;
  const float* yp = y + (size_t)b * DIM * NSP + n;
  float acc[8] = {0.f, 0.f, 0.f, 0.f, 0.f, 0.f, 0.f, 0.f};
#pragma unroll 1
  for (int c0 = 0; c0 < DIM; c0 += 32) {
    float yc[32];
#pragma unroll
    for (int cc = 0; cc < 32; ++cc) yc[cc] = yp[(size_t)(c0 + cc) * NSP];
#pragma unroll
    for (int cc = 0; cc < 32; ++cc)
#pragma unroll
      for (int i = 0; i < 8; ++i)
        acc[i] += w[(HID + oc * 8 + i) * DIM + c0 + cc] * yc[cc];
  }
  if (oc < 16) {
#pragma unroll
    for (int i = 0; i < 8; ++i)
      Kf[((size_t)b * HID + oc * 8 + i) * NSP + n] = acc[i];
  } else {
#pragma unroll
    for (int i = 0; i < 8; ++i)
      Vb[((size_t)b * HID + (oc - 16) * 8 + i) * NSP + n] = __float2bfloat16(acc[i]);
  }
}

// ---------------- row norms (over spatial axis) for Q and K ----------------
__global__ __launch_bounds__(256) void k_norms(const float* __restrict__ Qf,
                                               const float* __restrict__ Kf,
                                               float* __restrict__ rn) {
  int row = blockIdx.x;  // 0..255 Q rows, 256..511 K rows
  const float* src = (row < 256 ? Qf + (size_t)row * NSP : Kf + (size_t)(row - 256) * NSP);
  float ss = 0.f;
  for (int i = threadIdx.x; i < NSP; i += 256) { float v = src[i]; ss += v * v; }
  for (int m = 32; m; m >>= 1) ss += __shfl_xor(ss, m);
  __shared__ float red[4];
  if ((threadIdx.x & 63) == 0) red[threadIdx.x >> 6] = ss;
  __syncthreads();
  if (threadIdx.x == 0) {
    float t = red[0] + red[1] + red[2] + red[3];
    rn[row] = 1.f / fmaxf(sqrtf(t), 1e-12f);
  }
}

// ---------------- normalize + transpose to [b,h,n,32] bf16 (Q gets exp2 scale) ----------------
__global__ __launch_bounds__(256) void k_ntr(const float* __restrict__ Qf,
                                             const float* __restrict__ Kf,
                                             const float* __restrict__ rn,
                                             __hip_bfloat16* __restrict__ Qt,
                                             __hip_bfloat16* __restrict__ Kt) {
  int id   = blockIdx.x;        // 2 tensors * 2 b * 4 h * 32 itiles
  int tens = id >> 8;
  int rem  = id & 255;
  int b = rem >> 7, h = (rem >> 5) & 3, it = rem & 31;
  const float* src = (tens ? Kf : Qf) + ((size_t)(b * HID + h * DIMH)) * NSP + it * 128;
  const float* rns = rn + tens * 256 + b * HID + h * DIMH;
  __hip_bfloat16* dst = (tens ? Kt : Qt) + ((size_t)(b * HEADS + h) * NSP + it * 128) * DIMH;

  __shared__ float tile[DIMH][132];
  int d  = threadIdx.x >> 3;
  int cb = (threadIdx.x & 7) * 16;
  float s = rns[d] * (tens ? 1.f : QSCALE_LOG2E);
#pragma unroll
  for (int k = 0; k < 16; ++k) tile[d][cb + k] = src[(size_t)d * NSP + cb + k] * s;
  __syncthreads();
  int i = threadIdx.x >> 1, dh = (threadIdx.x & 1) * 16;
  unsigned outw[8];
#pragma unroll
  for (int k = 0; k < 8; ++k) {
    __hip_bfloat16 a = __float2bfloat16(tile[dh + 2 * k][i]);
    __hip_bfloat16 c = __float2bfloat16(tile[dh + 2 * k + 1][i]);
    unsigned lo = *(unsigned short*)&a, hi = *(unsigned short*)&c;
    outw[k] = lo | (hi << 16);
  }
  *(uint4*)(dst + i * DIMH + dh)     = *(uint4*)outw;
  *(uint4*)(dst + i * DIMH + dh + 8) = *(uint4*)(outw + 4);
}

// ---------------- flash attention: 32x32x16 MFMA, in-register softmax ----------------
__device__ __forceinline__ unsigned cvtpk_bf16(float a, float b) {
  unsigned d;
  asm("v_cvt_pk_bf16_f32 %0, %1, %2" : "=v"(d) : "v"(a), "v"(b));
  return d;
}

struct K4 { s16x8 k[4]; };
struct V4 { s16x8 v[4]; };

__device__ __forceinline__ K4 ldK(const __hip_bfloat16* kp, int j0) {
  K4 f;
#pragma unroll
  for (int s2 = 0; s2 < 2; ++s2)
#pragma unroll
    for (int kh = 0; kh < 2; ++kh)
      f.k[s2 * 2 + kh] = *(const s16x8*)(kp + (size_t)(j0 + s2 * 32) * DIMH + kh * 16);
  return f;
}
__device__ __forceinline__ V4 ldV(const __hip_bfloat16* vp, int j0) {
  V4 f;
#pragma unroll
  for (int cc = 0; cc < 4; ++cc)
    f.v[cc] = *(const s16x8*)(vp + j0 + cc * 16);
  return f;
}

// One 32(q-rows) x 32(j) subtile: QK^T (2 MFMA), exp2, pack, PV (2 MFMA).
__device__ __forceinline__ void attn_sub(s16x8 k0, s16x8 k1, s16x8 v0, s16x8 v1,
                                         const s16x8* qb, f32x16& O, float& lsum) {
  f32x16 z = {};
  f32x16 s = __builtin_amdgcn_mfma_f32_32x32x16_bf16(k0, qb[0], z, 0, 0, 0);
  s        = __builtin_amdgcn_mfma_f32_32x32x16_bf16(k1, qb[1], s, 0, 0, 0);
  float p[16];
#pragma unroll
  for (int r = 0; r < 16; ++r) p[r] = __builtin_amdgcn_exp2f(s[r]);
#pragma unroll
  for (int r = 0; r < 16; ++r) lsum += p[r];
  unsigned wA[4], wB[4];
#pragma unroll
  for (int m = 0; m < 4; ++m) {
    wA[m] = cvtpk_bf16(p[4 * m], p[4 * m + 1]);
    wB[m] = cvtpk_bf16(p[4 * m + 2], p[4 * m + 3]);
  }
#define PV_CHUNK(c, vfrag)                                                     \
  {                                                                            \
    unsigned a0 = wA[2 * (c)], a1 = wA[2 * (c) + 1];                           \
    unsigned b0 = wB[2 * (c)], b1 = wB[2 * (c) + 1];                           \
    asm("v_permlane32_swap_b32 %0, %1" : "+v"(a0), "+v"(a1));                  \
    asm("v_permlane32_swap_b32 %0, %1" : "+v"(b0), "+v"(b1));                  \
    union { unsigned u[4]; s16x8 v; } pa;                                      \
    pa.u[0] = a0; pa.u[1] = b0; pa.u[2] = a1; pa.u[3] = b1;                    \
    O = __builtin_amdgcn_mfma_f32_32x32x16_bf16(pa.v, vfrag, O, 0, 0, 0);      \
  }
  PV_CHUNK(0, v0);
  PV_CHUNK(1, v1);
#undef PV_CHUNK
}

// block = 4 waves (one 32-row q-tile, 4-way j split), grid = 8 bh * 128 rtiles.
// Output written channel-major: Ot2[(bh*32+d)*NSP + n] via LDS transpose.
__global__ __launch_bounds__(256, 4) void k_attn(const __hip_bfloat16* __restrict__ Qt,
                                                 const __hip_bfloat16* __restrict__ Kt,
                                                 const __hip_bfloat16* __restrict__ Vb,
                                                 float* __restrict__ Ot2) {
  int bid = blockIdx.x;
  int swz = (bid & 7) * 128 + (bid >> 3);   // 1024 blocks, XCD-contiguous
  int bh = swz >> 7, rt = swz & 127;
  int tid = threadIdx.x, lane = tid & 63, wave = tid >> 6;  // wave = j-quarter
  int l31 = lane & 31, hi = lane >> 5;
  int i0 = rt * 32;

  const __hip_bfloat16* kp = Kt + ((size_t)bh * NSP + l31) * DIMH + hi * 8;
  const __hip_bfloat16* vp = Vb + ((size_t)bh * DIMH + l31) * NSP + hi * 8;
  const __hip_bfloat16* qp = Qt + ((size_t)bh * NSP + i0 + l31) * DIMH + hi * 8;
  s16x8 qb[2] = { *(const s16x8*)qp, *(const s16x8*)(qp + 16) };

  f32x16 O = {};
  float lsum = 0.f;
  int jbase = wave * 1024;

  K4 ka = ldK(kp, jbase);
  for (int t = 0; t < 16; t += 2) {
    V4 va = ldV(vp, jbase + t * 64);
    K4 kb = ldK(kp, jbase + (t + 1) * 64);
    attn_sub(ka.k[0], ka.k[1], va.v[0], va.v[1], qb, O, lsum);
    attn_sub(ka.k[2], ka.k[3], va.v[2], va.v[3], qb, O, lsum);
    V4 vb = ldV(vp, jbase + (t + 1) * 64);
    ka = ldK(kp, jbase + ((t + 2) & 15) * 64);  // wraps harmlessly on last iter
    attn_sub(kb.k[0], kb.k[1], vb.v[0], vb.v[1], qb, O, lsum);
    attn_sub(kb.k[2], kb.k[3], vb.v[2], vb.v[3], qb, O, lsum);
  }

  // ---- merge 4 j-quarters, divide by row sums, transpose to channel-major ----
  __shared__ float Olds[3][16][68];
  __shared__ float Llds[4][64];
  float lw = lsum + __shfl_xor(lsum, 32);   // per-row sum (row = l31 within quarter)
  if (wave) {
#pragma unroll
    for (int r = 0; r < 16; ++r) Olds[wave - 1][r][lane] = O[r];
    Llds[wave][lane] = lw;
  }
  __syncthreads();
  if (wave == 0) {
    float ltot = lw + Llds[1][lane] + Llds[2][lane] + Llds[3][lane];
    if (hi == 0) Llds[0][l31] = ltot;       // reindex by row (same-wave DS order)
#pragma unroll
    for (int r = 0; r < 16; ++r) {
      int i = (r & 3) + 8 * (r >> 2) + 4 * hi;
      float li = Llds[0][i];
      Olds[0][r][lane] = (O[r] + Olds[0][r][lane] + Olds[1][r][lane] + Olds[2][r][lane]) / li;
    }
  }
  __syncthreads();
  // store: 32 d x 32 n; lanes cover n (coalesced 128B per d-row)
  {
    int n = tid & 31, dgrp = tid >> 5;       // dgrp 0..7, 4 d each
    int r = (n & 3) | ((n >> 3) << 2);
    int h2 = (n >> 2) & 1;
    float* obase = Ot2 + ((size_t)bh * DIMH) * NSP + i0 + n;
#pragma unroll
    for (int k2 = 0; k2 < 4; ++k2) {
      int d = dgrp * 4 + k2;
      obase[(size_t)d * NSP] = Olds[0][r][h2 * 32 + d];
    }
  }
}

// ---------------- output projection: clean channel GEMM over Ot2 ----------------
// grid = 32 oc (4 outs) x 64 ct, block 128.
__global__ __launch_bounds__(128, 4) void k_proj(const float* __restrict__ Ot2,
                                                 const float* __restrict__ w,
                                                 const float* __restrict__ bias,
                                                 float* __restrict__ out) {
  int ct = blockIdx.x & 63, oc = blockIdx.x >> 6;
  int g = ct * 128 + threadIdx.x;
  int b = g >> 12, n = g & 4095;
  const float* op = Ot2 + (size_t)b * HID * NSP + n;
  float acc[4];
#pragma unroll
  for (int i = 0; i < 4; ++i) acc[i] = bias[oc * 4 + i];
#pragma unroll 1
  for (int c0 = 0; c0 < HID; c0 += 32) {
    float hc[32];
#pragma unroll
    for (int cc = 0; cc < 32; ++cc) hc[cc] = op[(size_t)(c0 + cc) * NSP];
#pragma unroll
    for (int cc = 0; cc < 32; ++cc)
#pragma unroll
      for (int i = 0; i < 4; ++i)
        acc[i] += w[(oc * 4 + i) * HID + c0 + cc] * hc[cc];
  }
  float* outb = out + (size_t)b * DIM * NSP + n;
#pragma unroll
  for (int i = 0; i < 4; ++i) outb[(size_t)(oc * 4 + i) * NSP] = acc[i];
}

extern "C" void kernel_launch(void* const* d_in, const int* in_sizes, int n_in,
                              void* d_out, int out_size, void* d_ws, size_t ws_size,
                              hipStream_t stream) {
  const float* x     = (const float*)d_in[0];
  const float* y     = (const float*)d_in[1];
  const float* w_qkv = (const float*)d_in[2];
  const float* w_out = (const float*)d_in[3];
  const float* b_out = (const float*)d_in[4];
  float* out = (float*)d_out;

  char* ws = (char*)d_ws;
  float* Qf           = (float*)(ws);                       // 4 MB
  float* Kf           = (float*)(ws + (4  << 20));          // 4 MB
  __hip_bfloat16* Vb  = (__hip_bfloat16*)(ws + (8  << 20)); // 2 MB
  __hip_bfloat16* Qt  = (__hip_bfloat16*)(ws + (10 << 20)); // 2 MB
  __hip_bfloat16* Kt  = (__hip_bfloat16*)(ws + (12 << 20)); // 2 MB
  float* Ot2          = (float*)(ws + (14 << 20));          // 4 MB (channel-major)
  float* rn           = (float*)(ws + (18 << 20));          // 2 KB

  k_gemm_q <<<2048, 128, 0, stream>>>(x, w_qkv, Qf);
  k_gemm_kv<<<2048, 128, 0, stream>>>(y, w_qkv, Kf, Vb);
  k_norms  <<<512,  256, 0, stream>>>(Qf, Kf, rn);
  k_ntr    <<<512,  256, 0, stream>>>(Qf, Kf, rn, Qt, Kt);
  k_attn   <<<1024, 256, 0, stream>>>(Qt, Kt, Vb, Ot2);
  k_proj   <<<2048, 128, 0, stream>>>(Ot2, w_out, b_out, out);
}